// Round 3
// baseline (531.653 us; speedup 1.0000x reference)
//
#include <hip/hip_runtime.h>
#include <stdint.h>

// d = 128, m = 128, K_cb = 4. Q = in_sizes[0]/128, N = in_sizes[1]/128.
//   prep_keys: per key row: numpy-exact vec_norm (pairwise tree), quantize,
//              residual, SEQUENTIAL-FMA fp32 sign dots (matches OpenBLAS sgemm),
//              emit Bhat[n][0:128]=bf16(vn*x_mse), Bhat[n][128:256]=bf16(sign*w)
//   prep_A:    Ahat[q][0:128]=bf16(query), Ahat[q][128:256]=bf16(query@S^T)
//   gemm_bt:   out = Ahat @ Bhat^T  (bf16 MFMA 16x16x32, fp32 out)
//              K fixed at 256; 1-D grid with XCD-aware swizzle so the 4 blocks
//              sharing one B-panel are consecutive on one XCD (L2 reuse).

typedef __attribute__((ext_vector_type(8))) short bf16x8;
typedef __attribute__((ext_vector_type(4))) float f32x4;

__device__ __forceinline__ uint16_t f2bf(float x) {
    uint32_t u = __builtin_bit_cast(uint32_t, x);
    uint32_t r = (u + 0x7fffu + ((u >> 16) & 1u)) >> 16;
    return (uint16_t)r;
}

__device__ __forceinline__ void load_lds16(const void* g, void* l) {
    __builtin_amdgcn_global_load_lds(
        (const __attribute__((address_space(1))) void*)g,
        (__attribute__((address_space(3))) void*)l, 16, 0, 0);
}

#define SLD 129   // S row stride in LDS: (j*129+i)%32 -> only 2-way conflicts (free)

// ---------------- phase 1: key preprocessing --------------------------------
// 512 blocks x 256 threads, 16 tiles x 16 rows each. LDS ~75 KB -> 2 blocks/CU.
__global__ __launch_bounds__(256) void prep_keys(
    const float* __restrict__ keys, const float* __restrict__ codebook,
    const float* __restrict__ S, uint16_t* __restrict__ Bhat, int N)
{
    __shared__ float S_lds[128 * SLD];   // 66048 B, row-major [j][i]
    __shared__ float r_rm[16 * 132];     // keys tile, then residual tile
    __shared__ float rtmp[128];          // pairwise partial sums
    __shared__ float vn_sh[16];
    __shared__ float w_sh[16];

    const int tid = threadIdx.x;
    const int lane = tid & 63;
    const float c0 = codebook[0], c1 = codebook[1], c2 = codebook[2], c3 = codebook[3];
    const float scale = 0.009791516697777346f;  // fl32(sqrt(pi/2)/128)

    // stage S row-major with stride 129 (scalar writes; once per block)
    for (int f = tid; f < 4096; f += 256) {
        float4 v = ((const float4*)S)[f];
        int j = f >> 5;
        int i0 = (f & 31) * 4;
        float* p = &S_lds[j * SLD + i0];
        p[0] = v.x; p[1] = v.y; p[2] = v.z; p[3] = v.w;
    }

    for (int tile = 0; tile < 16; ++tile) {
        const int n0 = blockIdx.x * 256 + tile * 16;
        __syncthreads();   // prior tile done (and S staging on tile 0)

        // 1. stage 16 key rows (coalesced float4)
        #pragma unroll
        for (int u = 0; u < 2; ++u) {
            int f = u * 256 + tid;
            int row = f >> 5;
            int i0 = (f & 31) * 4;
            float4 v = ((const float4*)(keys + (size_t)(n0 + row) * 128))[f & 31];
            *(float4*)&r_rm[row * 132 + i0] = v;
        }
        __syncthreads();

        // 2. numpy pairwise_sum stage A: 8 accumulators/row, 16 sequential adds
        //    each (square rounded separately -> contract off)
        if (tid < 128) {
            int row = tid >> 3, k = tid & 7;
            const float* x = &r_rm[row * 132];
            float a;
            {
                #pragma clang fp contract(off)
                float x0 = x[k];
                a = x0 * x0;
                for (int t = 1; t < 16; ++t) {
                    float xv = x[t * 8 + k];
                    a = a + xv * xv;
                }
            }
            rtmp[tid] = a;
        }
        __syncthreads();

        // 3. numpy combine tree + IEEE sqrt
        if (tid < 16) {
            const float* r = &rtmp[tid * 8];
            float res = ((r[0] + r[1]) + (r[2] + r[3])) + ((r[4] + r[5]) + (r[6] + r[7]));
            vn_sh[tid] = sqrtf(res);
        }
        __syncthreads();

        // 4. quantize + residual + Bhat part1 + r_norm
        {
            int row = tid >> 4, i0 = (tid & 15) * 8;
            float vn = vn_sh[row];
            float denom = vn + 1e-8f;
            float rsq = 0.f;
            uint32_t pk[4];
            float rloc[8];
            #pragma unroll
            for (int u = 0; u < 8; ++u) {
                float xv = r_rm[row * 132 + i0 + u];
                float xn = xv / denom;                     // IEEE division
                float b = c0, d = fabsf(xn - c0), t;       // first-min argmin
                t = fabsf(xn - c1); if (t < d) { d = t; b = c1; }
                t = fabsf(xn - c2); if (t < d) { d = t; b = c2; }
                t = fabsf(xn - c3); if (t < d) { d = t; b = c3; }
                float rv = xn - b;
                rloc[u] = rv;
                rsq += rv * rv;
                uint32_t bv = f2bf(vn * b);
                if (u & 1) pk[u >> 1] |= bv << 16; else pk[u >> 1] = bv;
            }
            *(uint4*)(Bhat + (size_t)(n0 + row) * 256 + i0) = *(uint4*)pk;
            *(float4*)&r_rm[row * 132 + i0] = *(float4*)&rloc[0];
            *(float4*)&r_rm[row * 132 + i0 + 4] = *(float4*)&rloc[4];
            #pragma unroll
            for (int off2 = 1; off2 < 16; off2 <<= 1) rsq += __shfl_xor(rsq, off2);
            if ((tid & 15) == 0) w_sh[row] = sqrtf(rsq) * scale * vn;
        }
        __syncthreads();

        // 5. sign dots: thread owns one j and 8 rows; each dot is ONE sequential
        //    fp32 fma chain over i=0..127 ascending (OpenBLAS sgemm order).
        //    unroll 8 -> ds_read offsets become immediates, readlane idx const.
        {
            const int rowgrp = tid >> 7;       // waves 0,1 -> rows 0-7; 2,3 -> 8-15
            const int j = tid & 127;
            float rr[8][2];
            #pragma unroll
            for (int k = 0; k < 8; ++k) {
                rr[k][0] = r_rm[(rowgrp * 8 + k) * 132 + lane];
                rr[k][1] = r_rm[(rowgrp * 8 + k) * 132 + 64 + lane];
            }
            float acc[8] = {0.f, 0.f, 0.f, 0.f, 0.f, 0.f, 0.f, 0.f};
            const float* Sj = &S_lds[j * SLD];
            #pragma unroll
            for (int h = 0; h < 2; ++h) {
                #pragma unroll 8
                for (int i = 0; i < 64; ++i) {
                    float sv = Sj[h * 64 + i];
                    #pragma unroll
                    for (int k = 0; k < 8; ++k) {
                        int rb = __builtin_amdgcn_readlane(
                            __builtin_bit_cast(int, rr[k][h]), i);
                        acc[k] = __builtin_fmaf(__builtin_bit_cast(float, rb), sv, acc[k]);
                    }
                }
            }
            #pragma unroll
            for (int k = 0; k < 8; ++k) {
                float wv = w_sh[rowgrp * 8 + k];
                float v = (acc[k] >= 0.f) ? wv : -wv;
                Bhat[(size_t)(n0 + rowgrp * 8 + k) * 256 + 128 + j] = f2bf(v);
            }
        }
    }
}

// ---------------- phase 1b: A preparation -----------------------------------
__global__ __launch_bounds__(256) void prep_A(
    const float* __restrict__ query, const float* __restrict__ S,
    uint16_t* __restrict__ Ahat)
{
    int gid = blockIdx.x * 256 + threadIdx.x;   // Q*128 threads
    int q = gid >> 7, j = gid & 127;
    const float4* qr = (const float4*)(query + (size_t)q * 128);
    const float4* sr = (const float4*)(S + (size_t)j * 128);
    float acc = 0.f;
    #pragma unroll
    for (int i = 0; i < 32; ++i) {
        float4 a = qr[i], b = sr[i];
        acc += a.x * b.x + a.y * b.y + a.z * b.z + a.w * b.w;
    }
    Ahat[(size_t)q * 256 + j] = f2bf(query[(size_t)q * 128 + j]);
    Ahat[(size_t)q * 256 + 128 + j] = f2bf(acc);
}

// ---------------- phase 2: C = Ahat @ Bhat^T  (bf16 MFMA, fp32 out) ----------
// K fixed at 256. 1-D grid; XCD swizzle: blocks sharing a B-panel land on the
// same XCD consecutively -> B read once into that XCD's L2, reused nbm-1 times.
__global__ __launch_bounds__(256) void gemm_bt(
    const uint16_t* __restrict__ A, const uint16_t* __restrict__ B,
    float* __restrict__ C, int N, int Q)
{
    __shared__ uint16_t Asl[128 * 64];
    __shared__ uint16_t Bsl[128 * 64];
    const int tid = threadIdx.x;
    const int lane = tid & 63, wid = tid >> 6;

    const int nbn = N >> 7, nbm = Q >> 7;
    const int f = blockIdx.x;
    int bm_idx, bn_idx;
    if ((nbn & 7) == 0) {
        const int xcd = f & 7, s = f >> 3;
        const int pxb = nbn >> 3;            // bn panels per XCD
        const int sq = s / nbm;
        bn_idx = xcd * pxb + sq;
        bm_idx = s - sq * nbm;
    } else {
        bn_idx = f % nbn;
        bm_idx = f / nbn;
    }
    const int bm = bm_idx * 128;
    const int bn = bn_idx * 128;

    const int wm = (wid & 1) * 64, wn = (wid >> 1) * 64;
    const int lrow = lane & 15, lquad = lane >> 4;
    f32x4 acc[4][4] = {};

    #pragma unroll
    for (int kc = 0; kc < 256; kc += 64) {
        __syncthreads();
        #pragma unroll
        for (int u = 0; u < 4; ++u) {
            int flat = u * 256 + tid;
            int row = flat >> 3, ch = flat & 7;
            load_lds16(A + (size_t)(bm + row) * 256 + kc + ch * 8, &Asl[flat * 8]);
            load_lds16(B + (size_t)(bn + row) * 256 + kc + ch * 8, &Bsl[flat * 8]);
        }
        __syncthreads();
        #pragma unroll
        for (int ks = 0; ks < 2; ++ks) {
            bf16x8 af[4], bfr[4];
            #pragma unroll
            for (int ff = 0; ff < 4; ++ff) {
                af[ff]  = *(const bf16x8*)&Asl[(wm + ff * 16 + lrow) * 64 + ks * 32 + lquad * 8];
                bfr[ff] = *(const bf16x8*)&Bsl[(wn + ff * 16 + lrow) * 64 + ks * 32 + lquad * 8];
            }
            #pragma unroll
            for (int i = 0; i < 4; ++i)
                #pragma unroll
                for (int j = 0; j < 4; ++j)
                    acc[i][j] = __builtin_amdgcn_mfma_f32_16x16x32_bf16(af[i], bfr[j], acc[i][j], 0, 0, 0);
        }
    }

    #pragma unroll
    for (int i = 0; i < 4; ++i) {
        int row = bm + wm + i * 16 + lquad * 4;
        #pragma unroll
        for (int j = 0; j < 4; ++j) {
            int col = bn + wn + j * 16 + lrow;
            float* cp = C + (size_t)row * N + col;
            #pragma unroll
            for (int r = 0; r < 4; ++r) cp[(size_t)r * N] = acc[i][j][r];
        }
    }
}

extern "C" void kernel_launch(void* const* d_in, const int* in_sizes, int n_in,
                              void* d_out, int out_size, void* d_ws, size_t ws_size,
                              hipStream_t stream) {
    const float* query    = (const float*)d_in[0];
    const float* keys     = (const float*)d_in[1];
    const float* codebook = (const float*)d_in[2];
    const float* S        = (const float*)d_in[3];
    const int Q = in_sizes[0] / 128;   // 512
    const int N = in_sizes[1] / 128;   // 131072

    uint16_t* Bhat = (uint16_t*)d_ws;                                  // N*256 bf16
    uint16_t* Ahat = (uint16_t*)((char*)d_ws + (size_t)N * 256 * 2);   // Q*256 bf16

    prep_keys<<<N / 256, 256, 0, stream>>>(keys, codebook, S, Bhat, N);
    prep_A<<<(Q * 128) / 256, 256, 0, stream>>>(query, S, Ahat);
    gemm_bt<<<(N / 128) * (Q / 128), 256, 0, stream>>>(Ahat, Bhat, (float*)d_out, N, Q);
}